// Round 10
// baseline (812.259 us; speedup 1.0000x reference)
//
#include <hip/hip_runtime.h>

#define U_NUMC 100000
#define I_NUMC 50000
#define NNODES 150000
#define EMB 64
#define NBATCH 8192
#define NB_I ((I_NUMC + 255) / 256)   // 196 blocks over item histogram
#define GRP 16                         // gathers in flight per wave

// ---------------- fused: zero hist + user row_ptr binary search ---------------
__global__ __launch_bounds__(256) void k_prep(const int* __restrict__ rows1, int E1,
                                              int* __restrict__ uptr,
                                              int* __restrict__ hist) {
    int g = blockIdx.x * blockDim.x + threadIdx.x;
    if (g < I_NUMC) hist[g] = 0;
    if (g <= U_NUMC) {
        int lo = 0, hi = E1;                 // first e with rows1[e] >= g
        while (lo < hi) {
            int mid = (lo + hi) >> 1;
            if (rows1[mid] < g) lo = mid + 1; else hi = mid;
        }
        uptr[g] = lo;
    }
}

// ---------------- histogram of items from first-half cols (= i + U_NUM) -------
__global__ __launch_bounds__(256) void k_hist(const int* __restrict__ cols1, int E1,
                                              int* __restrict__ hist) {
    int e = blockIdx.x * blockDim.x + threadIdx.x;
    if (e >= E1) return;
    atomicAdd(&hist[cols1[e] - U_NUMC], 1);
}

// ---------------- hierarchical scan: (1) per-block sums ----------------
__global__ __launch_bounds__(256) void k_scan1(const int* __restrict__ hist,
                                               int* __restrict__ bsum) {
    int b = blockIdx.x, t = threadIdx.x;
    int idx = b * 256 + t;
    int v = (idx < I_NUMC) ? hist[idx] : 0;
    #pragma unroll
    for (int o = 32; o; o >>= 1) v += __shfl_xor(v, o);
    __shared__ int ws4[4];
    if ((t & 63) == 0) ws4[t >> 6] = v;
    __syncthreads();
    if (t == 0) bsum[b] = ws4[0] + ws4[1] + ws4[2] + ws4[3];
}

// ---------------- (2) scan the 196 block sums (single block) ----------------
__global__ __launch_bounds__(256) void k_scan2(const int* __restrict__ bsum,
                                               int* __restrict__ boff,
                                               int* __restrict__ iptr) {
    __shared__ int lds[256];
    int t = threadIdx.x;
    int v = (t < NB_I) ? bsum[t] : 0;
    int x = v;
    #pragma unroll
    for (int o = 1; o < 256; o <<= 1) {
        lds[t] = x; __syncthreads();
        int y = (t >= o) ? lds[t - o] : 0; __syncthreads();
        x += y;
    }
    if (t < NB_I) boff[t] = x - v;           // exclusive block offset
    if (t == 255) iptr[I_NUMC] = x;          // grand total
}

// ---------------- (3) per-block rescan + write iptr & cursor ----------------
__global__ __launch_bounds__(256) void k_scan3(const int* __restrict__ hist,
                                               const int* __restrict__ boff,
                                               int* __restrict__ iptr,
                                               int* __restrict__ cursor) {
    __shared__ int lds[256];
    int b = blockIdx.x, t = threadIdx.x;
    int idx = b * 256 + t;
    int v = (idx < I_NUMC) ? hist[idx] : 0;
    int x = v;
    #pragma unroll
    for (int o = 1; o < 256; o <<= 1) {
        lds[t] = x; __syncthreads();
        int y = (t >= o) ? lds[t - o] : 0; __syncthreads();
        x += y;
    }
    if (idx < I_NUMC) {
        int excl = boff[b] + x - v;
        iptr[idx] = excl;
        cursor[idx] = excl;
    }
}

// ------- XCD-class-filtered scatter into exact item-CSR positions -------------
// Block class = blockIdx.x & 7 (round-robin block->XCD). Class k handles only
// items with (i>>3)&7 == k, so each 8-item destination window (~2.5 KB) is
// written by a single XCD -> full-line merge in that XCD's L2.
__global__ __launch_bounds__(256) void k_scatter(const int* __restrict__ rows1,
                                                 const int* __restrict__ cols1,
                                                 const float* __restrict__ vals1,
                                                 int E1,
                                                 int* __restrict__ cursor,
                                                 int2* __restrict__ item_uv) {
    const int cls  = blockIdx.x & 7;
    const int bsub = blockIdx.x >> 3;
    const int nb   = gridDim.x >> 3;         // blocks per class
    const int E4   = E1 >> 2;
    const int4* c4p = (const int4*)cols1;
    for (int q = bsub * 256 + threadIdx.x; q < E4; q += nb * 256) {
        int4 c4 = c4p[q];
        #pragma unroll
        for (int t = 0; t < 4; ++t) {
            int cv = (t == 0) ? c4.x : (t == 1) ? c4.y : (t == 2) ? c4.z : c4.w;
            int i = cv - U_NUMC;
            if (((i >> 3) & 7) != cls) continue;
            int e = q * 4 + t;
            int pos = atomicAdd(&cursor[i], 1);
            item_uv[pos] = make_int2(rows1[e], __float_as_int(vals1[e]));
        }
    }
    // tail edges (E1 not multiple of 4): handled by bsub==0 block of each class
    if (bsub == 0) {
        int e = E4 * 4 + threadIdx.x;
        if (e < E1) {
            int i = cols1[e] - U_NUMC;
            if (((i >> 3) & 7) == cls) {
                int pos = atomicAdd(&cursor[i], 1);
                item_uv[pos] = make_int2(rows1[e], __float_as_int(vals1[e]));
            }
        }
    }
}

// ---------------- SpMM (CSR-vector): one wave per row, lane = dim -------------
// GRP=16 clamp-predicated groups: no serial tail; 16 independent gathers in
// flight; edge stream via wide uniform s_loads. Bijective XCD swizzle maps
// consecutive rows (lockstep sorted-column walks) to the same XCD for L2
// band locality.
template <int FIRST>
__global__ __launch_bounds__(256) void k_spmm(const float* __restrict__ uE,
                                              const float* __restrict__ iE,
                                              const float* __restrict__ f,
                                              float* __restrict__ fn,
                                              const int* __restrict__ uptr,
                                              const int* __restrict__ cols1,
                                              const float* __restrict__ vals1,
                                              const int* __restrict__ iptr,
                                              const int2* __restrict__ item_uv) {
    // bijective XCD swizzle (m204 variant): contiguous grid chunk per XCD
    int nwg = gridDim.x;
    int q = nwg >> 3, r = nwg & 7;
    int xcd = blockIdx.x & 7, sub = blockIdx.x >> 3;
    int swz = (xcd < r ? xcd * (q + 1) : r * (q + 1) + (xcd - r) * q) + sub;

    int wave = ((swz << 8) + (int)threadIdx.x) >> 6;
    int lane = threadIdx.x & 63;
    if (wave >= NNODES) return;

    const bool isUser = (wave < U_NUMC);
    int beg, end;
    if (isUser) { beg = uptr[wave];           end = uptr[wave + 1]; }
    else        { int i = wave - U_NUMC; beg = iptr[i]; end = iptr[i + 1]; }
    beg = __builtin_amdgcn_readfirstlane(beg);
    end = __builtin_amdgcn_readfirstlane(end);

    const float* fb;
    if (FIRST) fb = isUser ? (iE - (size_t)U_NUMC * EMB) : uE;
    else       fb = f;

    float s[GRP];
    #pragma unroll
    for (int t = 0; t < GRP; ++t) s[t] = 0.f;

    if (isUser) {
        for (int j = beg; j < end; j += GRP) {
            int   cc[GRP];
            float vv[GRP];
            #pragma unroll
            for (int t = 0; t < GRP; ++t) {
                int idx = j + t;
                int ld = min(idx, end - 1);
                cc[t] = cols1[ld];                   // uniform scalar loads
                vv[t] = (idx < end) ? vals1[ld] : 0.f;
            }
            float l[GRP];
            #pragma unroll
            for (int t = 0; t < GRP; ++t)
                l[t] = fb[(size_t)cc[t] * EMB + lane];   // 16 gathers in flight
            #pragma unroll
            for (int t = 0; t < GRP; ++t) s[t] += vv[t] * l[t];
        }
    } else {
        for (int j = beg; j < end; j += GRP) {
            int   cc[GRP];
            float vv[GRP];
            #pragma unroll
            for (int t = 0; t < GRP; ++t) {
                int idx = j + t;
                int ld = min(idx, end - 1);
                int2 e = item_uv[ld];                // uniform s_load_dwordx2
                cc[t] = e.x;
                vv[t] = (idx < end) ? __int_as_float(e.y) : 0.f;
            }
            float l[GRP];
            #pragma unroll
            for (int t = 0; t < GRP; ++t)
                l[t] = fb[(size_t)cc[t] * EMB + lane];
            #pragma unroll
            for (int t = 0; t < GRP; ++t) s[t] += vv[t] * l[t];
        }
    }
    float sum = 0.f;
    #pragma unroll
    for (int t = 0; t < GRP; ++t) sum += s[t];
    fn[(size_t)wave * EMB + lane] = sum;
}

// ------- batched dot: final = (base + g1 + g2 + g3)/4, dot = sum/16 ----------
__global__ __launch_bounds__(256) void k_out(const float* __restrict__ uE,
                                             const float* __restrict__ iE,
                                             const float* __restrict__ g1,
                                             const float* __restrict__ g2,
                                             const float* __restrict__ g3,
                                             const int* __restrict__ userIdx,
                                             const int* __restrict__ itemIdx,
                                             float* __restrict__ out) {
    int wave = (blockIdx.x * blockDim.x + threadIdx.x) >> 6;
    int lane = threadIdx.x & 63;
    if (wave >= NBATCH) return;
    int u  = userIdx[wave];
    int it = itemIdx[wave];
    size_t ou = (size_t)u * EMB + lane;
    size_t oi = (size_t)(U_NUMC + it) * EMB + lane;
    float a = uE[ou] + g1[ou] + g2[ou] + g3[ou];
    float b = iE[(size_t)it * EMB + lane] + g1[oi] + g2[oi] + g3[oi];
    float p = a * b;
    #pragma unroll
    for (int o = 32; o; o >>= 1) p += __shfl_xor(p, o);
    if (lane == 0) out[wave] = p * (1.0f / 16.0f);   // (sum/4)·(sum/4)
}

extern "C" void kernel_launch(void* const* d_in, const int* in_sizes, int n_in,
                              void* d_out, int out_size, void* d_ws, size_t ws_size,
                              hipStream_t stream) {
    const float* uE      = (const float*)d_in[0];
    const float* iE      = (const float*)d_in[1];
    const int*   rows    = (const int*)d_in[2];    // [E], first half sorted by u
    const int*   cols    = (const int*)d_in[3];    // [E], first half = i + U_NUM
    const float* vals    = (const float*)d_in[4];  // [E], symmetric halves
    const int*   userIdx = (const int*)d_in[5];
    const int*   itemIdx = (const int*)d_in[6];
    const int E  = in_sizes[2];
    const int E1 = E / 2;

    char* ws = (char*)d_ws;
    size_t off = 0;
    auto alloc = [&](size_t bytes) -> void* {
        off = (off + 255) & ~(size_t)255;
        void* p = ws + off;
        off += bytes;
        return p;
    };
    float* g1      = (float*)alloc((size_t)NNODES * EMB * 4);
    float* g2      = (float*)alloc((size_t)NNODES * EMB * 4);
    float* g3      = (float*)alloc((size_t)NNODES * EMB * 4);
    int*   uptr    = (int*)alloc((size_t)(U_NUMC + 1) * 4);
    int*   iptr    = (int*)alloc((size_t)(I_NUMC + 1) * 4);
    int*   hist    = (int*)alloc((size_t)I_NUMC * 4);
    int*   cursor  = (int*)alloc((size_t)I_NUMC * 4);
    int*   bsum    = (int*)alloc((size_t)NB_I * 4);
    int*   boff    = (int*)alloc((size_t)NB_I * 4);
    int2*  item_uv = (int2*)alloc((size_t)E1 * 8);

    // fused hist-zero + user row_ptr; then index structures
    k_prep<<<(U_NUMC + 256) / 256, 256, 0, stream>>>(rows, E1, uptr, hist);
    k_hist<<<(E1 + 255) / 256, 256, 0, stream>>>(cols, E1, hist);
    k_scan1<<<NB_I, 256, 0, stream>>>(hist, bsum);
    k_scan2<<<1, 256, 0, stream>>>(bsum, boff, iptr);
    k_scan3<<<NB_I, 256, 0, stream>>>(hist, boff, iptr, cursor);
    k_scatter<<<2048, 256, 0, stream>>>(rows, cols, vals, E1, cursor, item_uv);

    // 3 propagation layers: g1 = A·feats, g2 = A·g1, g3 = A·g2
    const int spmm_blocks = NNODES / 4;      // 4 waves (rows) per 256-thr block
    k_spmm<1><<<spmm_blocks, 256, 0, stream>>>(uE, iE, nullptr, g1,
                                               uptr, cols, vals, iptr, item_uv);
    k_spmm<0><<<spmm_blocks, 256, 0, stream>>>(uE, iE, g1, g2,
                                               uptr, cols, vals, iptr, item_uv);
    k_spmm<0><<<spmm_blocks, 256, 0, stream>>>(uE, iE, g2, g3,
                                               uptr, cols, vals, iptr, item_uv);

    // final batched dot products
    k_out<<<NBATCH / 4, 256, 0, stream>>>(uE, iE, g1, g2, g3,
                                          userIdx, itemIdx, (float*)d_out);
}

// Round 13
// 671.236 us; speedup vs baseline: 1.2101x; 1.2101x over previous
//
#include <hip/hip_runtime.h>

#define U_NUMC 100000
#define I_NUMC 50000
#define NNODES 150000
#define EMB 64
#define NBATCH 8192
#define NB_I ((I_NUMC + 255) / 256)   // 196 blocks over item histogram
#define SCAT_NB 2048                   // scatter-role blocks in fused kernel

// ---------------- fused: zero hist + user row_ptr binary search ---------------
__global__ __launch_bounds__(256) void k_prep(const int* __restrict__ rows1, int E1,
                                              int* __restrict__ uptr,
                                              int* __restrict__ hist) {
    int g = blockIdx.x * blockDim.x + threadIdx.x;
    if (g < I_NUMC) hist[g] = 0;
    if (g <= U_NUMC) {
        int lo = 0, hi = E1;                 // first e with rows1[e] >= g
        while (lo < hi) {
            int mid = (lo + hi) >> 1;
            if (rows1[mid] < g) lo = mid + 1; else hi = mid;
        }
        uptr[g] = lo;
    }
}

// ---------------- histogram of items from first-half cols (= i + U_NUM) -------
__global__ __launch_bounds__(256) void k_hist(const int* __restrict__ cols1, int E1,
                                              int* __restrict__ hist) {
    int e = blockIdx.x * blockDim.x + threadIdx.x;
    if (e >= E1) return;
    atomicAdd(&hist[cols1[e] - U_NUMC], 1);
}

// ---------------- hierarchical scan: (1) per-block sums ----------------
__global__ __launch_bounds__(256) void k_scan1(const int* __restrict__ hist,
                                               int* __restrict__ bsum) {
    int b = blockIdx.x, t = threadIdx.x;
    int idx = b * 256 + t;
    int v = (idx < I_NUMC) ? hist[idx] : 0;
    #pragma unroll
    for (int o = 32; o; o >>= 1) v += __shfl_xor(v, o);
    __shared__ int ws4[4];
    if ((t & 63) == 0) ws4[t >> 6] = v;
    __syncthreads();
    if (t == 0) bsum[b] = ws4[0] + ws4[1] + ws4[2] + ws4[3];
}

// ---------------- (2) scan the 196 block sums (single block) ----------------
__global__ __launch_bounds__(256) void k_scan2(const int* __restrict__ bsum,
                                               int* __restrict__ boff,
                                               int* __restrict__ iptr) {
    __shared__ int lds[256];
    int t = threadIdx.x;
    int v = (t < NB_I) ? bsum[t] : 0;
    int x = v;
    #pragma unroll
    for (int o = 1; o < 256; o <<= 1) {
        lds[t] = x; __syncthreads();
        int y = (t >= o) ? lds[t - o] : 0; __syncthreads();
        x += y;
    }
    if (t < NB_I) boff[t] = x - v;           // exclusive block offset
    if (t == 255) iptr[I_NUMC] = x;          // grand total
}

// ---------------- (3) per-block rescan + write iptr & cursor ----------------
__global__ __launch_bounds__(256) void k_scan3(const int* __restrict__ hist,
                                               const int* __restrict__ boff,
                                               int* __restrict__ iptr,
                                               int* __restrict__ cursor) {
    __shared__ int lds[256];
    int b = blockIdx.x, t = threadIdx.x;
    int idx = b * 256 + t;
    int v = (idx < I_NUMC) ? hist[idx] : 0;
    int x = v;
    #pragma unroll
    for (int o = 1; o < 256; o <<= 1) {
        lds[t] = x; __syncthreads();
        int y = (t >= o) ? lds[t - o] : 0; __syncthreads();
        x += y;
    }
    if (idx < I_NUMC) {
        int excl = boff[b] + x - v;
        iptr[idx] = excl;
        cursor[idx] = excl;
    }
}

// ------- FUSED: [blocks 0..SCAT_NB) XCD-class-filtered scatter  ∥  -----------
// ------- [blocks SCAT_NB..) layer-1 user-row SpMM (needs only uptr) ----------
// Independent after scan3: user rows never read item_uv. Scatter's ~100 us
// hides under the user-half gather work. Bodies written out directly (no
// shared device fn — the R11 template/forceinline/nullptr combo ICE'd clang).
__global__ __launch_bounds__(256) void k_scat_userL1(const int* __restrict__ rows1,
                                                     const int* __restrict__ cols1,
                                                     const float* __restrict__ vals1,
                                                     int E1,
                                                     int* __restrict__ cursor,
                                                     int2* __restrict__ item_uv,
                                                     const float* __restrict__ uE,
                                                     const float* __restrict__ iE,
                                                     float* __restrict__ g1,
                                                     const int* __restrict__ uptr) {
    if (blockIdx.x < SCAT_NB) {
        // ---- scatter role (exact R8 body; nb fixed to SCAT_NB/8) ----
        const int cls  = blockIdx.x & 7;
        const int bsub = blockIdx.x >> 3;
        const int nb   = SCAT_NB >> 3;       // 256 blocks per class
        const int E4   = E1 >> 2;
        const int4* c4p = (const int4*)cols1;
        for (int q = bsub * 256 + (int)threadIdx.x; q < E4; q += nb * 256) {
            int4 c4 = c4p[q];
            #pragma unroll
            for (int t = 0; t < 4; ++t) {
                int cv = (t == 0) ? c4.x : (t == 1) ? c4.y : (t == 2) ? c4.z : c4.w;
                int i = cv - U_NUMC;
                if (((i >> 3) & 7) != cls) continue;
                int e = q * 4 + t;
                int pos = atomicAdd(&cursor[i], 1);
                item_uv[pos] = make_int2(rows1[e], __float_as_int(vals1[e]));
            }
        }
        if (bsub == 0) {                     // tail edges (E1 % 4)
            int e = E4 * 4 + (int)threadIdx.x;
            if (e < E1) {
                int i = cols1[e] - U_NUMC;
                if (((i >> 3) & 7) == cls) {
                    int pos = atomicAdd(&cursor[i], 1);
                    item_uv[pos] = make_int2(rows1[e], __float_as_int(vals1[e]));
                }
            }
        }
    } else {
        // ---- layer-1 user-row SpMM role (user path only) ----
        int w = ((blockIdx.x - SCAT_NB) * 256 + (int)threadIdx.x) >> 6;
        if (w >= U_NUMC) return;
        int lane = threadIdx.x & 63;
        int beg = uptr[w], end = uptr[w + 1];
        beg = __builtin_amdgcn_readfirstlane(beg);
        end = __builtin_amdgcn_readfirstlane(end);
        const float* fb = iE - (size_t)U_NUMC * EMB;  // cols1 holds i+U_NUM
        float s0 = 0.f, s1 = 0.f, s2 = 0.f, s3 = 0.f;
        float s4 = 0.f, s5 = 0.f, s6 = 0.f, s7 = 0.f;
        int j = beg;
        for (; j + 8 <= end; j += 8) {
            #pragma unroll
            for (int t = 0; t < 8; ++t) {
                int   c = cols1[j + t];
                float v = vals1[j + t];
                float l = fb[(size_t)c * EMB + lane];
                if (t == 0) s0 += v * l; else if (t == 1) s1 += v * l;
                else if (t == 2) s2 += v * l; else if (t == 3) s3 += v * l;
                else if (t == 4) s4 += v * l; else if (t == 5) s5 += v * l;
                else if (t == 6) s6 += v * l; else s7 += v * l;
            }
        }
        for (; j < end; ++j)
            s0 += vals1[j] * fb[(size_t)cols1[j] * EMB + lane];
        float sum = ((s0 + s1) + (s2 + s3)) + ((s4 + s5) + (s6 + s7));
        g1[(size_t)w * EMB + lane] = sum;
    }
}

// ---------------- layer-1 item rows: gather users from uE ----------------
__global__ __launch_bounds__(256) void k_spmm_itemL1(const float* __restrict__ uE,
                                                     float* __restrict__ g1,
                                                     const int* __restrict__ iptr,
                                                     const int2* __restrict__ item_uv) {
    int w = (blockIdx.x * 256 + (int)threadIdx.x) >> 6;
    if (w >= I_NUMC) return;
    int lane = threadIdx.x & 63;
    int beg = iptr[w], end = iptr[w + 1];
    beg = __builtin_amdgcn_readfirstlane(beg);
    end = __builtin_amdgcn_readfirstlane(end);
    float s0 = 0.f, s1 = 0.f, s2 = 0.f, s3 = 0.f;
    float s4 = 0.f, s5 = 0.f, s6 = 0.f, s7 = 0.f;
    int j = beg;
    for (; j + 8 <= end; j += 8) {
        #pragma unroll
        for (int t = 0; t < 8; ++t) {
            int2 e = item_uv[j + t];
            float v = __int_as_float(e.y);
            float l = uE[(size_t)e.x * EMB + lane];
            if (t == 0) s0 += v * l; else if (t == 1) s1 += v * l;
            else if (t == 2) s2 += v * l; else if (t == 3) s3 += v * l;
            else if (t == 4) s4 += v * l; else if (t == 5) s5 += v * l;
            else if (t == 6) s6 += v * l; else s7 += v * l;
        }
    }
    for (; j < end; ++j) {
        int2 e = item_uv[j];
        s0 += __int_as_float(e.y) * uE[(size_t)e.x * EMB + lane];
    }
    float sum = ((s0 + s1) + (s2 + s3)) + ((s4 + s5) + (s6 + s7));
    g1[(size_t)(U_NUMC + w) * EMB + lane] = sum;
}

// ---------------- full-layer SpMM (layers 2,3): exact R8 body, f input -------
__global__ __launch_bounds__(256) void k_spmm(const float* __restrict__ f,
                                              float* __restrict__ fn,
                                              const int* __restrict__ uptr,
                                              const int* __restrict__ cols1,
                                              const float* __restrict__ vals1,
                                              const int* __restrict__ iptr,
                                              const int2* __restrict__ item_uv) {
    int wave = (blockIdx.x * blockDim.x + threadIdx.x) >> 6;
    int lane = threadIdx.x & 63;
    if (wave >= NNODES) return;

    const bool isUser = (wave < U_NUMC);
    int beg, end;
    if (isUser) { beg = uptr[wave];           end = uptr[wave + 1]; }
    else        { int i = wave - U_NUMC; beg = iptr[i]; end = iptr[i + 1]; }
    beg = __builtin_amdgcn_readfirstlane(beg);
    end = __builtin_amdgcn_readfirstlane(end);

    float s0 = 0.f, s1 = 0.f, s2 = 0.f, s3 = 0.f;
    float s4 = 0.f, s5 = 0.f, s6 = 0.f, s7 = 0.f;
    int j = beg;
    if (isUser) {
        for (; j + 8 <= end; j += 8) {
            #pragma unroll
            for (int t = 0; t < 8; ++t) {
                int   c = cols1[j + t];
                float v = vals1[j + t];
                float l = f[(size_t)c * EMB + lane];
                if (t == 0) s0 += v * l; else if (t == 1) s1 += v * l;
                else if (t == 2) s2 += v * l; else if (t == 3) s3 += v * l;
                else if (t == 4) s4 += v * l; else if (t == 5) s5 += v * l;
                else if (t == 6) s6 += v * l; else s7 += v * l;
            }
        }
        for (; j < end; ++j)
            s0 += vals1[j] * f[(size_t)cols1[j] * EMB + lane];
    } else {
        for (; j + 8 <= end; j += 8) {
            #pragma unroll
            for (int t = 0; t < 8; ++t) {
                int2 e = item_uv[j + t];
                float v = __int_as_float(e.y);
                float l = f[(size_t)e.x * EMB + lane];
                if (t == 0) s0 += v * l; else if (t == 1) s1 += v * l;
                else if (t == 2) s2 += v * l; else if (t == 3) s3 += v * l;
                else if (t == 4) s4 += v * l; else if (t == 5) s5 += v * l;
                else if (t == 6) s6 += v * l; else s7 += v * l;
            }
        }
        for (; j < end; ++j) {
            int2 e = item_uv[j];
            s0 += __int_as_float(e.y) * f[(size_t)e.x * EMB + lane];
        }
    }
    float sum = ((s0 + s1) + (s2 + s3)) + ((s4 + s5) + (s6 + s7));
    fn[(size_t)wave * EMB + lane] = sum;
}

// ------- batched dot: final = (base + g1 + g2 + g3)/4, dot = sum/16 ----------
__global__ __launch_bounds__(256) void k_out(const float* __restrict__ uE,
                                             const float* __restrict__ iE,
                                             const float* __restrict__ g1,
                                             const float* __restrict__ g2,
                                             const float* __restrict__ g3,
                                             const int* __restrict__ userIdx,
                                             const int* __restrict__ itemIdx,
                                             float* __restrict__ out) {
    int wave = (blockIdx.x * blockDim.x + threadIdx.x) >> 6;
    int lane = threadIdx.x & 63;
    if (wave >= NBATCH) return;
    int u  = userIdx[wave];
    int it = itemIdx[wave];
    size_t ou = (size_t)u * EMB + lane;
    size_t oi = (size_t)(U_NUMC + it) * EMB + lane;
    float a = uE[ou] + g1[ou] + g2[ou] + g3[ou];
    float b = iE[(size_t)it * EMB + lane] + g1[oi] + g2[oi] + g3[oi];
    float p = a * b;
    #pragma unroll
    for (int o = 32; o; o >>= 1) p += __shfl_xor(p, o);
    if (lane == 0) out[wave] = p * (1.0f / 16.0f);   // (sum/4)·(sum/4)
}

extern "C" void kernel_launch(void* const* d_in, const int* in_sizes, int n_in,
                              void* d_out, int out_size, void* d_ws, size_t ws_size,
                              hipStream_t stream) {
    const float* uE      = (const float*)d_in[0];
    const float* iE      = (const float*)d_in[1];
    const int*   rows    = (const int*)d_in[2];    // [E], first half sorted by u
    const int*   cols    = (const int*)d_in[3];    // [E], first half = i + U_NUM
    const float* vals    = (const float*)d_in[4];  // [E], symmetric halves
    const int*   userIdx = (const int*)d_in[5];
    const int*   itemIdx = (const int*)d_in[6];
    const int E  = in_sizes[2];
    const int E1 = E / 2;

    char* ws = (char*)d_ws;
    size_t off = 0;
    auto alloc = [&](size_t bytes) -> void* {
        off = (off + 255) & ~(size_t)255;
        void* p = ws + off;
        off += bytes;
        return p;
    };
    float* g1      = (float*)alloc((size_t)NNODES * EMB * 4);
    float* g2      = (float*)alloc((size_t)NNODES * EMB * 4);
    float* g3      = (float*)alloc((size_t)NNODES * EMB * 4);
    int*   uptr    = (int*)alloc((size_t)(U_NUMC + 1) * 4);
    int*   iptr    = (int*)alloc((size_t)(I_NUMC + 1) * 4);
    int*   hist    = (int*)alloc((size_t)I_NUMC * 4);
    int*   cursor  = (int*)alloc((size_t)I_NUMC * 4);
    int*   bsum    = (int*)alloc((size_t)NB_I * 4);
    int*   boff    = (int*)alloc((size_t)NB_I * 4);
    int2*  item_uv = (int2*)alloc((size_t)E1 * 8);

    // index structures (hist-zero + uptr fused)
    k_prep<<<(U_NUMC + 256) / 256, 256, 0, stream>>>(rows, E1, uptr, hist);
    k_hist<<<(E1 + 255) / 256, 256, 0, stream>>>(cols, E1, hist);
    k_scan1<<<NB_I, 256, 0, stream>>>(hist, bsum);
    k_scan2<<<1, 256, 0, stream>>>(bsum, boff, iptr);
    k_scan3<<<NB_I, 256, 0, stream>>>(hist, boff, iptr, cursor);

    // fused: item-CSR scatter  ∥  layer-1 user-row SpMM
    const int userL1_blocks = U_NUMC / 4;    // 4 rows (waves) per 256-thr block
    k_scat_userL1<<<SCAT_NB + userL1_blocks, 256, 0, stream>>>(
        rows, cols, vals, E1, cursor, item_uv, uE, iE, g1, uptr);

    // layer-1 item rows (needs item_uv), then full layers 2 and 3
    k_spmm_itemL1<<<I_NUMC / 4, 256, 0, stream>>>(uE, g1, iptr, item_uv);
    k_spmm<<<NNODES / 4, 256, 0, stream>>>(g1, g2, uptr, cols, vals, iptr, item_uv);
    k_spmm<<<NNODES / 4, 256, 0, stream>>>(g2, g3, uptr, cols, vals, iptr, item_uv);

    // final batched dot products
    k_out<<<NBATCH / 4, 256, 0, stream>>>(uE, iE, g1, g2, g3,
                                          userIdx, itemIdx, (float*)d_out);
}